// Round 22
// baseline (70378.400 us; speedup 1.0000x reference)
//
#include <hip/hip_runtime.h>

typedef unsigned int u32;
typedef unsigned short u16;

__device__ __forceinline__ float wb2f(u16 u) {
  union { u32 i; float f; } c; c.i = ((u32)u) << 16; return c.f;
}
__device__ __forceinline__ u16 wf2b(float f) {
  union { float ff; u32 i; } c; c.ff = f;
  u32 x = c.i;
  return (u16)((x + 0x7FFFu + ((x >> 16) & 1u)) >> 16);  // RNE
}
__device__ __forceinline__ float wlk(float e) { return e > 0.f ? e : 0.2f * e; }
__device__ __forceinline__ float wrl(float v) { return (v < 0.f) ? 0.f : v; }

// ---------- H[r,o] = sum_k x[r,k] * W[o,k] ----------
__global__ void w22_mm(const void* xp, int n, int isbf, const float* W, float* H) {
  long t = (long)blockIdx.x * 256 + threadIdx.x;
  if (t >= (long)n * 128) return;
  int r = (int)(t >> 7), o = (int)(t & 127);
  const float* wr = W + (size_t)o * 128;
  float s = 0.f;
  if (isbf) {
    const u16* x = (const u16*)xp + (size_t)r * 128;
    for (int k = 0; k < 128; ++k) s = fmaf(wb2f(x[k]), wr[k], s);
  } else {
    const float* x = (const float*)xp + (size_t)r * 128;
    for (int k = 0; k < 128; ++k) s = fmaf(x[k], wr[k], s);
  }
  H[t] = s;
}

// ---------- al[i] = sum_o H[i,o] * a[o] ----------
__global__ void w22_av(const float* H, int n, const float* a, float* al) {
  int wid = (int)(((unsigned)blockIdx.x * blockDim.x + threadIdx.x) >> 6);
  int lane = threadIdx.x & 63;
  if (wid >= n) return;
  float s = H[(size_t)wid * 128 + lane] * a[lane]
          + H[(size_t)wid * 128 + lane + 64] * a[lane + 64];
  for (int off = 32; off; off >>= 1) s += __shfl_xor(s, off);
  if (lane == 0) al[wid] = s;
}

// ---------- literal GAT accumulate (one relation, dst row d) ----------
__device__ void w22_acc(int d, int E, const int* ei, const float* als, float av,
                        const float* H, int lane, float& t0, float& t1) {
  const int* src = ei;
  const int* dst = ei + E;
  float mx = -INFINITY;
  for (int e = lane; e < E; e += 64)
    if (dst[e] == d) mx = fmaxf(mx, wlk(als[src[e]] + av));
  for (int off = 32; off; off >>= 1) mx = fmaxf(mx, __shfl_xor(mx, off));
  if (mx == -INFINITY) return;
  float dn = 0.f;
  for (int e = lane; e < E; e += 64)
    if (dst[e] == d) dn += expf(wlk(als[src[e]] + av) - mx);
  for (int off = 32; off; off >>= 1) dn += __shfl_xor(dn, off);
  float inv = 1.f / (dn + 1e-16f);
  for (int base = 0; base < E; base += 64) {
    int e = base + lane;
    bool m = (e < E) && (dst[e] == d);
    unsigned long long bal = __ballot(m);
    while (bal) {
      int l = (int)(__ffsll((long long)bal) - 1);
      bal &= bal - 1;
      int s = src[base + l];
      float w = expf(wlk(als[s] + av) - mx) * inv;
      t0 = fmaf(w, H[(size_t)s * 128 + 2 * lane], t0);
      t1 = fmaf(w, H[(size_t)s * 128 + 2 * lane + 1], t1);
    }
  }
}

// layer-1 gather: writes bf16-packed u32 into workspace X1
__global__ void w22_ag_bf(int Nd, int EA, const int* eiA, const float* alsA,
                          const float* aldA, const float* HA, const float* bA,
                          int EB, const int* eiB, const float* alsB, const float* aldB,
                          const float* HB, const float* bB, u32* out) {
  int wid = (int)(((unsigned)blockIdx.x * blockDim.x + threadIdx.x) >> 6);
  int lane = threadIdx.x & 63;
  if (wid >= Nd) return;
  float t0 = 0.f, t1 = 0.f;
  w22_acc(wid, EA, eiA, alsA, aldA[wid], HA, lane, t0, t1);
  if (eiB) w22_acc(wid, EB, eiB, alsB, aldB[wid], HB, lane, t0, t1);
  float b0 = bA[2 * lane], b1 = bA[2 * lane + 1];
  if (bB) { b0 += bB[2 * lane]; b1 += bB[2 * lane + 1]; }
  u16 lo = wf2b(wrl(t0 + b0));
  u16 hi = wf2b(wrl(t1 + b1));
  out[(size_t)wid * 64 + lane] = (u32)lo | ((u32)hi << 16);
}

// layer-2 gather: writes FLOAT32 into d_out (the 19-round fix)
__global__ void w22_ag_f32(int Nd, int EA, const int* eiA, const float* alsA,
                           const float* aldA, const float* HA, const float* bA,
                           int EB, const int* eiB, const float* alsB, const float* aldB,
                           const float* HB, const float* bB, float2* out) {
  int wid = (int)(((unsigned)blockIdx.x * blockDim.x + threadIdx.x) >> 6);
  int lane = threadIdx.x & 63;
  if (wid >= Nd) return;
  float t0 = 0.f, t1 = 0.f;
  w22_acc(wid, EA, eiA, alsA, aldA[wid], HA, lane, t0, t1);
  if (eiB) w22_acc(wid, EB, eiB, alsB, aldB[wid], HB, lane, t0, t1);
  float b0 = bA[2 * lane], b1 = bA[2 * lane + 1];
  if (bB) { b0 += bB[2 * lane]; b1 += bB[2 * lane + 1]; }
  float2 v;
  v.x = wrl(t0 + b0);
  v.y = wrl(t1 + b1);
  out[(size_t)wid * 64 + lane] = v;
}

static void w22_prep(hipStream_t st, const void* xs, int Ns, int bfS,
                     const void* xd, int Nd, int bfD,
                     const float* Wd, const float* ad, const float* Ws, const float* as,
                     float* H, float* ALS, float* ALD) {
  w22_mm<<<(int)(((long)Nd * 128 + 255) / 256), 256, 0, st>>>(xd, Nd, bfD, Wd, H);
  w22_av<<<(Nd + 3) / 4, 256, 0, st>>>(H, Nd, ad, ALD);
  w22_mm<<<(int)(((long)Ns * 128 + 255) / 256), 256, 0, st>>>(xs, Ns, bfS, Ws, H);
  w22_av<<<(Ns + 3) / 4, 256, 0, st>>>(H, Ns, as, ALS);
}

extern "C" void kernel_launch(void* const* d_in, const int* in_sizes, int n_in,
                              void* d_out, int out_size, void* d_ws, size_t ws_size,
                              hipStream_t stream) {
  static const int exp_sizes[21] = {
      2048, 2560000, 6400000, 12800000, 10240000,
      40000, 100000, 40000, 100000, 400000, 320000, 160000, 100000,
      262144, 262144, 2048, 2048, 2048, 49152, 384, 384};
  bool ok = (n_in == 21);
  if (ok) { for (int i = 0; i < 21; ++i) { if (in_sizes[i] != exp_sizes[i]) { ok = false; break; } } }
  if (!ok) { hipMemsetAsync(d_out, 0x42, (size_t)out_size * 4, stream); return; }
  if (out_size != 19200000) { hipMemsetAsync(d_out, 0x40, (size_t)out_size * 4, stream); return; }

  const float* x_dc   = (const float*)d_in[0];
  const float* x_host = (const float*)d_in[1];
  const float* x_vm   = (const float*)d_in[2];
  const float* x_task = (const float*)d_in[3];
  const float* x_inst = (const float*)d_in[4];
  const int* ei0 = (const int*)d_in[5];
  const int* ei1 = (const int*)d_in[6];
  const int* ei2 = (const int*)d_in[7];
  const int* ei3 = (const int*)d_in[8];
  const int* ei4 = (const int*)d_in[9];
  const int* ei5 = (const int*)d_in[10];
  const int* ei6 = (const int*)d_in[11];
  const int* ei7 = (const int*)d_in[12];
  const float* Wsrc = (const float*)d_in[13];
  const float* Wdst = (const float*)d_in[14];
  const float* atts = (const float*)d_in[15];
  const float* attd = (const float*)d_in[16];
  const float* bias = (const float*)d_in[17];

  char* p0 = (char*)d_ws;
  char* p = p0;
  float* ALSa = (float*)p;  p += 100000 * 4;
  float* ALSb = (float*)p;  p += 100000 * 4;
  float* ALDa = (float*)p;  p += 100000 * 4;
  float* ALDb = (float*)p;  p += 100000 * 4;
  p = p0 + (((size_t)(p - p0) + 255) & ~(size_t)255);
  float* HA = (float*)p;    p += (size_t)100000 * 128 * 4;
  float* HB = (float*)p;    p += (size_t)80000 * 128 * 4;
  u16* X1 = (u16*)p;        p += (size_t)250016 * 256;
  size_t need = (size_t)(p - p0);
  if (ws_size < need) { hipMemsetAsync(d_out, 0x44, (size_t)out_size * 4, stream); return; }

  u16* Xdc = X1;
  u16* Xhost = X1 + (size_t)16 * 128;
  u16* Xvm = X1 + (size_t)20016 * 128;
  u16* Xtask = X1 + (size_t)70016 * 128;
  u16* Xinst = X1 + (size_t)170016 * 128;

  // ---- layer 1 (fp32 inputs -> bf16 X1 workspace) ----
  w22_prep(stream, x_dc, 16, 0, x_host, 20000, 0,
           Wdst + 0 * 16384, attd + 0 * 128, Wsrc + 0 * 16384, atts + 0 * 128,
           HA, ALSa, ALDa);
  w22_prep(stream, x_vm, 50000, 0, x_host, 20000, 0,
           Wdst + 7 * 16384, attd + 7 * 128, Wsrc + 7 * 16384, atts + 7 * 128,
           HB, ALSb, ALDb);
  w22_ag_bf<<<5001, 256, 0, stream>>>(20000, 20000, ei0, ALSa, ALDa, HA, bias + 0 * 128,
                                      50000, ei7, ALSb, ALDb, HB, bias + 7 * 128, (u32*)Xhost);
  w22_prep(stream, x_dc, 16, 0, x_vm, 50000, 0,
           Wdst + 1 * 16384, attd + 1 * 128, Wsrc + 1 * 16384, atts + 1 * 128,
           HA, ALSa, ALDa);
  w22_prep(stream, x_inst, 80000, 0, x_vm, 50000, 0,
           Wdst + 6 * 16384, attd + 6 * 128, Wsrc + 6 * 16384, atts + 6 * 128,
           HB, ALSb, ALDb);
  w22_ag_bf<<<12501, 256, 0, stream>>>(50000, 50000, ei1, ALSa, ALDa, HA, bias + 1 * 128,
                                       80000, ei6, ALSb, ALDb, HB, bias + 6 * 128, (u32*)Xvm);
  w22_prep(stream, x_task, 100000, 0, x_task, 100000, 0,
           Wdst + 4 * 16384, attd + 4 * 128, Wsrc + 4 * 16384, atts + 4 * 128,
           HA, ALSa, ALDa);
  w22_ag_bf<<<25001, 256, 0, stream>>>(100000, 200000, ei4, ALSa, ALDa, HA, bias + 4 * 128,
                                       0, (const int*)0, (const float*)0, (const float*)0,
                                       (const float*)0, (const float*)0, (u32*)Xtask);
  w22_prep(stream, x_task, 100000, 0, x_inst, 80000, 0,
           Wdst + 5 * 16384, attd + 5 * 128, Wsrc + 5 * 16384, atts + 5 * 128,
           HA, ALSa, ALDa);
  w22_ag_bf<<<20001, 256, 0, stream>>>(80000, 160000, ei5, ALSa, ALDa, HA, bias + 5 * 128,
                                       0, (const int*)0, (const float*)0, (const float*)0,
                                       (const float*)0, (const float*)0, (u32*)Xinst);
  w22_prep(stream, x_host, 20000, 0, x_dc, 16, 0,
           Wdst + 2 * 16384, attd + 2 * 128, Wsrc + 2 * 16384, atts + 2 * 128,
           HA, ALSa, ALDa);
  w22_prep(stream, x_vm, 50000, 0, x_dc, 16, 0,
           Wdst + 3 * 16384, attd + 3 * 128, Wsrc + 3 * 16384, atts + 3 * 128,
           HB, ALSb, ALDb);
  w22_ag_bf<<<4, 256, 0, stream>>>(16, 20000, ei2, ALSa, ALDa, HA, bias + 2 * 128,
                                   50000, ei3, ALSb, ALDb, HB, bias + 3 * 128, (u32*)Xdc);

  // ---- layer 2 (bf16 X1 inputs -> FLOAT32 d_out) ----
  float* out = (float*)d_out;
  w22_prep(stream, Xdc, 16, 1, Xhost, 20000, 1,
           Wdst + 8 * 16384, attd + 8 * 128, Wsrc + 8 * 16384, atts + 8 * 128,
           HA, ALSa, ALDa);
  w22_prep(stream, Xvm, 50000, 1, Xhost, 20000, 1,
           Wdst + 15 * 16384, attd + 15 * 128, Wsrc + 15 * 16384, atts + 15 * 128,
           HB, ALSb, ALDb);
  w22_ag_f32<<<5001, 256, 0, stream>>>(20000, 20000, ei0, ALSa, ALDa, HA, bias + 8 * 128,
                                       50000, ei7, ALSb, ALDb, HB, bias + 15 * 128,
                                       (float2*)out);
  w22_prep(stream, Xdc, 16, 1, Xvm, 50000, 1,
           Wdst + 9 * 16384, attd + 9 * 128, Wsrc + 9 * 16384, atts + 9 * 128,
           HA, ALSa, ALDa);
  w22_prep(stream, Xinst, 80000, 1, Xvm, 50000, 1,
           Wdst + 14 * 16384, attd + 14 * 128, Wsrc + 14 * 16384, atts + 14 * 128,
           HB, ALSb, ALDb);
  w22_ag_f32<<<12501, 256, 0, stream>>>(50000, 50000, ei1, ALSa, ALDa, HA, bias + 9 * 128,
                                        80000, ei6, ALSb, ALDb, HB, bias + 14 * 128,
                                        (float2*)(out + (size_t)20000 * 128));
  w22_prep(stream, Xtask, 100000, 1, Xinst, 80000, 1,
           Wdst + 13 * 16384, attd + 13 * 128, Wsrc + 13 * 16384, atts + 13 * 128,
           HA, ALSa, ALDa);
  w22_ag_f32<<<20001, 256, 0, stream>>>(80000, 160000, ei5, ALSa, ALDa, HA, bias + 13 * 128,
                                        0, (const int*)0, (const float*)0, (const float*)0,
                                        (const float*)0, (const float*)0,
                                        (float2*)(out + (size_t)70000 * 128));
}

// Round 23
// 9477.664 us; speedup vs baseline: 7.4257x; 7.4257x over previous
//
#include <hip/hip_runtime.h>

typedef unsigned int u32;
typedef unsigned short u16;

__device__ __forceinline__ float xb2f(u16 u) {
  union { u32 i; float f; } c; c.i = ((u32)u) << 16; return c.f;
}
__device__ __forceinline__ u16 xf2b(float f) {
  union { float ff; u32 i; } c; c.ff = f;
  u32 x = c.i;
  return (u16)((x + 0x7FFFu + ((x >> 16) & 1u)) >> 16);  // RNE
}
__device__ __forceinline__ float xlk(float e) { return e > 0.f ? e : 0.2f * e; }
__device__ __forceinline__ float xrl(float v) { return (v < 0.f) ? 0.f : v; }

// ---------- VD[vid][k] = sum_o attd[vid][o] * Wdst[vid][o,k]  (16 vids) ----------
__global__ void x23_vecs(const float* Wdst, const float* attd, float* VD) {
  int vid = blockIdx.x, k = threadIdx.x;
  const float* W = Wdst + (size_t)vid * 16384;
  const float* a = attd + (size_t)vid * 128;
  float s = 0.f;
  for (int o = 0; o < 128; ++o) s = fmaf(a[o], W[o * 128 + k], s);
  VD[vid * 128 + k] = s;
}

// ---------- H[r,o] = sum_k x[r,k] * W[o,k] ----------
__global__ void x23_mm(const void* xp, int n, int isbf, const float* W, float* H) {
  long t = (long)blockIdx.x * 256 + threadIdx.x;
  if (t >= (long)n * 128) return;
  int r = (int)(t >> 7), o = (int)(t & 127);
  const float* wr = W + (size_t)o * 128;
  float s = 0.f;
  if (isbf) {
    const u16* x = (const u16*)xp + (size_t)r * 128;
    for (int k = 0; k < 128; ++k) s = fmaf(xb2f(x[k]), wr[k], s);
  } else {
    const float* x = (const float*)xp + (size_t)r * 128;
    for (int k = 0; k < 128; ++k) s = fmaf(x[k], wr[k], s);
  }
  H[t] = s;
}

// ---------- al[i] = sum_o H[i,o] * a[o]  (from materialized H) ----------
__global__ void x23_av(const float* H, int n, const float* a, float* al) {
  int wid = (int)(((unsigned)blockIdx.x * blockDim.x + threadIdx.x) >> 6);
  int lane = threadIdx.x & 63;
  if (wid >= n) return;
  float s = H[(size_t)wid * 128 + lane] * a[lane]
          + H[(size_t)wid * 128 + lane + 64] * a[lane + 64];
  for (int off = 32; off; off >>= 1) s += __shfl_xor(s, off);
  if (lane == 0) al[wid] = s;
}

// ---------- al_d[i] = x[i,:] . v   (dst-side shortcut: v = Wd^T a_d) ----------
__global__ void x23_mv(const void* xp, int n, int isbf, const float* v, float* al) {
  int wid = (int)(((unsigned)blockIdx.x * blockDim.x + threadIdx.x) >> 6);
  int lane = threadIdx.x & 63;
  if (wid >= n) return;
  float x0, x1;
  if (isbf) {
    const u16* x = (const u16*)xp + (size_t)wid * 128;
    x0 = xb2f(x[lane]); x1 = xb2f(x[lane + 64]);
  } else {
    const float* x = (const float*)xp + (size_t)wid * 128;
    x0 = x[lane]; x1 = x[lane + 64];
  }
  float s = x0 * v[lane] + x1 * v[lane + 64];
  for (int off = 32; off; off >>= 1) s += __shfl_xor(s, off);
  if (lane == 0) al[wid] = s;
}

// ---------- CSR build: count -> scan -> place (int atomics) ----------
__global__ void x23_count(const int* dst, int E, int* cnt) {
  int e = blockIdx.x * 256 + threadIdx.x;
  if (e < E) atomicAdd(&cnt[dst[e]], 1);
}
__global__ void x23_scan(const int* cnt, int Nd, int E, int* rp) {
  __shared__ int ls[1024];
  int t = threadIdx.x;
  int chunk = (Nd + 1023) >> 10;
  int b0 = t * chunk, b1 = min(b0 + chunk, Nd);
  int s = 0;
  for (int i = b0; i < b1; ++i) s += cnt[i];
  ls[t] = s;
  __syncthreads();
  if (t == 0) { int run = 0; for (int i = 0; i < 1024; ++i) { int tmp = ls[i]; ls[i] = run; run += tmp; } }
  __syncthreads();
  int run = ls[t];
  for (int i = b0; i < b1; ++i) { rp[i] = run; run += cnt[i]; }
  if (t == 0) rp[Nd] = E;
}
__global__ void x23_place(const int* dst, int E, const int* rp, int* fill, int* eidx) {
  int e = blockIdx.x * 256 + threadIdx.x;
  if (e >= E) return;
  int d = dst[e];
  eidx[rp[d] + atomicAdd(&fill[d], 1)] = e;
}

// ---------- CSR gather accumulate (one relation, dst row d) ----------
__device__ void x23_acc(int d, const int* rp, const int* eidx, const int* src,
                        const float* als, float av, const float* H, int lane,
                        float& t0, float& t1) {
  int lo = rp[d], hi = rp[d + 1];
  if (lo >= hi) return;
  float mx = -INFINITY;
  for (int i = lo + lane; i < hi; i += 64) mx = fmaxf(mx, xlk(als[src[eidx[i]]] + av));
  for (int off = 32; off; off >>= 1) mx = fmaxf(mx, __shfl_xor(mx, off));
  float dn = 0.f;
  for (int i = lo + lane; i < hi; i += 64) dn += expf(xlk(als[src[eidx[i]]] + av) - mx);
  for (int off = 32; off; off >>= 1) dn += __shfl_xor(dn, off);
  float inv = 1.f / (dn + 1e-16f);
  for (int i = lo; i < hi; ++i) {  // wave-uniform walk of own edges
    int s = src[eidx[i]];
    float w = expf(xlk(als[s] + av) - mx) * inv;
    t0 = fmaf(w, H[(size_t)s * 128 + 2 * lane], t0);
    t1 = fmaf(w, H[(size_t)s * 128 + 2 * lane + 1], t1);
  }
}

// layer-1: bf16-packed X1 out
__global__ void x23_ag_bf(int Nd, const int* rpA, const int* eixA, const int* sA,
                          const float* alsA, const float* aldA, const float* HA, const float* bA,
                          const int* rpB, const int* eixB, const int* sB,
                          const float* alsB, const float* aldB, const float* HB, const float* bB,
                          u32* out) {
  int wid = (int)(((unsigned)blockIdx.x * blockDim.x + threadIdx.x) >> 6);
  int lane = threadIdx.x & 63;
  if (wid >= Nd) return;
  float t0 = 0.f, t1 = 0.f;
  x23_acc(wid, rpA, eixA, sA, alsA, aldA[wid], HA, lane, t0, t1);
  if (rpB) x23_acc(wid, rpB, eixB, sB, alsB, aldB[wid], HB, lane, t0, t1);
  float b0 = bA[2 * lane], b1 = bA[2 * lane + 1];
  if (bB) { b0 += bB[2 * lane]; b1 += bB[2 * lane + 1]; }
  u16 lo = xf2b(xrl(t0 + b0));
  u16 hi = xf2b(xrl(t1 + b1));
  out[(size_t)wid * 64 + lane] = (u32)lo | ((u32)hi << 16);
}

// layer-2: float32 out (d_out)
__global__ void x23_ag_f32(int Nd, const int* rpA, const int* eixA, const int* sA,
                           const float* alsA, const float* aldA, const float* HA, const float* bA,
                           const int* rpB, const int* eixB, const int* sB,
                           const float* alsB, const float* aldB, const float* HB, const float* bB,
                           float2* out) {
  int wid = (int)(((unsigned)blockIdx.x * blockDim.x + threadIdx.x) >> 6);
  int lane = threadIdx.x & 63;
  if (wid >= Nd) return;
  float t0 = 0.f, t1 = 0.f;
  x23_acc(wid, rpA, eixA, sA, alsA, aldA[wid], HA, lane, t0, t1);
  if (rpB) x23_acc(wid, rpB, eixB, sB, alsB, aldB[wid], HB, lane, t0, t1);
  float b0 = bA[2 * lane], b1 = bA[2 * lane + 1];
  if (bB) { b0 += bB[2 * lane]; b1 += bB[2 * lane + 1]; }
  float2 v;
  v.x = xrl(t0 + b0);
  v.y = xrl(t1 + b1);
  out[(size_t)wid * 64 + lane] = v;
}

extern "C" void kernel_launch(void* const* d_in, const int* in_sizes, int n_in,
                              void* d_out, int out_size, void* d_ws, size_t ws_size,
                              hipStream_t stream) {
  static const int exp_sizes[21] = {
      2048, 2560000, 6400000, 12800000, 10240000,
      40000, 100000, 40000, 100000, 400000, 320000, 160000, 100000,
      262144, 262144, 2048, 2048, 2048, 49152, 384, 384};
  bool ok = (n_in == 21);
  if (ok) { for (int i = 0; i < 21; ++i) { if (in_sizes[i] != exp_sizes[i]) { ok = false; break; } } }
  if (!ok) { hipMemsetAsync(d_out, 0x42, (size_t)out_size * 4, stream); return; }
  if (out_size != 19200000) { hipMemsetAsync(d_out, 0x40, (size_t)out_size * 4, stream); return; }

  const void* xin[5];
  for (int t = 0; t < 5; ++t) xin[t] = d_in[t];
  const int* ei[8];
  for (int r = 0; r < 8; ++r) ei[r] = (const int*)d_in[5 + r];
  const float* Wsrc = (const float*)d_in[13];
  const float* Wdst = (const float*)d_in[14];
  const float* atts = (const float*)d_in[15];
  const float* attd = (const float*)d_in[16];
  const float* bias = (const float*)d_in[17];

  static const int Ecnt[8] = {20000, 50000, 20000, 50000, 200000, 160000, 80000, 50000};
  static const int Ndst[8] = {20000, 50000, 16, 16, 100000, 80000, 50000, 20000};

  // ---- workspace ----
  char* p0 = (char*)d_ws;
  char* p = p0;
  int* CNT = (int*)p;       p += 100000 * 4;
  float* VD = (float*)p;    p += 16 * 128 * 4;
  float* ALSa = (float*)p;  p += 100000 * 4;
  float* ALSb = (float*)p;  p += 100000 * 4;
  float* ALDa = (float*)p;  p += 100000 * 4;
  float* ALDb = (float*)p;  p += 100000 * 4;
  int* RP[8];
  for (int r = 0; r < 8; ++r) { RP[r] = (int*)p; p += (size_t)(Ndst[r] + 16) * 4; }
  int* EIX[8];
  for (int r = 0; r < 8; ++r) { EIX[r] = (int*)p; p += (size_t)Ecnt[r] * 4; }
  p = p0 + (((size_t)(p - p0) + 255) & ~(size_t)255);
  float* HA = (float*)p;    p += (size_t)100000 * 128 * 4;
  float* HB = (float*)p;    p += (size_t)80000 * 128 * 4;
  u16* X1 = (u16*)p;        p += (size_t)250016 * 256;
  size_t need = (size_t)(p - p0);
  if (ws_size < need) { hipMemsetAsync(d_out, 0x44, (size_t)out_size * 4, stream); return; }

  u16* Xdc = X1;
  u16* Xhost = X1 + (size_t)16 * 128;
  u16* Xvm = X1 + (size_t)20016 * 128;
  u16* Xtask = X1 + (size_t)70016 * 128;
  u16* Xinst = X1 + (size_t)170016 * 128;

  // ---- CSR build (once; reused by both layers) ----
  for (int r = 0; r < 8; ++r) {
    const int* dstp = ei[r] + Ecnt[r];
    hipMemsetAsync(CNT, 0, (size_t)Ndst[r] * 4, stream);
    x23_count<<<(Ecnt[r] + 255) / 256, 256, 0, stream>>>(dstp, Ecnt[r], CNT);
    x23_scan<<<1, 1024, 0, stream>>>(CNT, Ndst[r], Ecnt[r], RP[r]);
    hipMemsetAsync(CNT, 0, (size_t)Ndst[r] * 4, stream);
    x23_place<<<(Ecnt[r] + 255) / 256, 256, 0, stream>>>(dstp, Ecnt[r], RP[r], CNT, EIX[r]);
  }
  x23_vecs<<<16, 128, 0, stream>>>(Wdst, attd, VD);

  // prep one relation: hs GEMM -> H, al_s from H, al_d via matvec
  auto prep = [&](int vid, const void* xs, int Ns, const void* xd, int Nd, int isbf,
                  float* H, float* ALS, float* ALD) {
    x23_mm<<<(int)(((long)Ns * 128 + 255) / 256), 256, 0, stream>>>(
        xs, Ns, isbf, Wsrc + (size_t)vid * 16384, H);
    x23_av<<<(Ns + 3) / 4, 256, 0, stream>>>(H, Ns, atts + (size_t)vid * 128, ALS);
    x23_mv<<<(Nd + 3) / 4, 256, 0, stream>>>(xd, Nd, isbf, VD + vid * 128, ALD);
  };
  auto brow = [&](int layer, int r) { return bias + (size_t)(layer * 8 + r) * 128; };

  // ================= layer 1 (fp32 inputs -> bf16 X1) =================
  // host <- dsho(r0: dc->host) + run_by(r7: vm->host)
  prep(0, xin[0], 16, xin[1], 20000, 0, HA, ALSa, ALDa);
  prep(7, xin[2], 50000, xin[1], 20000, 0, HB, ALSb, ALDb);
  x23_ag_bf<<<5001, 256, 0, stream>>>(20000, RP[0], EIX[0], ei[0], ALSa, ALDa, HA, brow(0, 0),
                                      RP[7], EIX[7], ei[7], ALSb, ALDb, HB, brow(0, 7),
                                      (u32*)Xhost);
  // vm <- dsvm(r1) + run_in(r6)
  prep(1, xin[0], 16, xin[2], 50000, 0, HA, ALSa, ALDa);
  prep(6, xin[4], 80000, xin[2], 50000, 0, HB, ALSb, ALDb);
  x23_ag_bf<<<12501, 256, 0, stream>>>(50000, RP[1], EIX[1], ei[1], ALSa, ALDa, HA, brow(0, 1),
                                       RP[6], EIX[6], ei[6], ALSb, ALDb, HB, brow(0, 6),
                                       (u32*)Xvm);
  // task <- depend(r4)
  prep(4, xin[3], 100000, xin[3], 100000, 0, HA, ALSa, ALDa);
  x23_ag_bf<<<25001, 256, 0, stream>>>(100000, RP[4], EIX[4], ei[4], ALSa, ALDa, HA, brow(0, 4),
                                       (const int*)0, (const int*)0, (const int*)0,
                                       (const float*)0, (const float*)0, (const float*)0,
                                       (const float*)0, (u32*)Xtask);
  // instance <- part_of(r5)
  prep(5, xin[3], 100000, xin[4], 80000, 0, HA, ALSa, ALDa);
  x23_ag_bf<<<20001, 256, 0, stream>>>(80000, RP[5], EIX[5], ei[5], ALSa, ALDa, HA, brow(0, 5),
                                       (const int*)0, (const int*)0, (const int*)0,
                                       (const float*)0, (const float*)0, (const float*)0,
                                       (const float*)0, (u32*)Xinst);
  // datacenter <- hods(r2) + vmds(r3)
  prep(2, xin[1], 20000, xin[0], 16, 0, HA, ALSa, ALDa);
  prep(3, xin[2], 50000, xin[0], 16, 0, HB, ALSb, ALDb);
  x23_ag_bf<<<4, 256, 0, stream>>>(16, RP[2], EIX[2], ei[2], ALSa, ALDa, HA, brow(0, 2),
                                   RP[3], EIX[3], ei[3], ALSb, ALDb, HB, brow(0, 3),
                                   (u32*)Xdc);

  // ================= layer 2 (bf16 X1 -> fp32 d_out) =================
  float* out = (float*)d_out;
  prep(8, Xdc, 16, Xhost, 20000, 1, HA, ALSa, ALDa);
  prep(15, Xvm, 50000, Xhost, 20000, 1, HB, ALSb, ALDb);
  x23_ag_f32<<<5001, 256, 0, stream>>>(20000, RP[0], EIX[0], ei[0], ALSa, ALDa, HA, brow(1, 0),
                                       RP[7], EIX[7], ei[7], ALSb, ALDb, HB, brow(1, 7),
                                       (float2*)out);
  prep(9, Xdc, 16, Xvm, 50000, 1, HA, ALSa, ALDa);
  prep(14, Xinst, 80000, Xvm, 50000, 1, HB, ALSb, ALDb);
  x23_ag_f32<<<12501, 256, 0, stream>>>(50000, RP[1], EIX[1], ei[1], ALSa, ALDa, HA, brow(1, 1),
                                        RP[6], EIX[6], ei[6], ALSb, ALDb, HB, brow(1, 6),
                                        (float2*)(out + (size_t)20000 * 128));
  prep(13, Xtask, 100000, Xinst, 80000, 1, HA, ALSa, ALDa);
  x23_ag_f32<<<20001, 256, 0, stream>>>(80000, RP[5], EIX[5], ei[5], ALSa, ALDa, HA, brow(1, 5),
                                        (const int*)0, (const int*)0, (const int*)0,
                                        (const float*)0, (const float*)0, (const float*)0,
                                        (const float*)0,
                                        (float2*)(out + (size_t)70000 * 128));
}